// Round 3
// baseline (371.901 us; speedup 1.0000x reference)
//
#include <hip/hip_runtime.h>

typedef unsigned short u16;
typedef unsigned int u32;
typedef __attribute__((ext_vector_type(8))) short bf16x8;
typedef __attribute__((ext_vector_type(4))) float f32x4;

#define D640 640

__device__ __forceinline__ float b2f(u16 u) {
  union { u32 i; float f; } x; x.i = ((u32)u) << 16; return x.f;
}
__device__ __forceinline__ u16 f2b(float f) {
  union { float f; u32 i; } x; x.f = f;
  u32 r = x.i + 0x7FFFu + ((x.i >> 16) & 1u);
  return (u16)(r >> 16);
}
__device__ __forceinline__ bf16x8 pack8(f32x4 lo, f32x4 hi) {
  bf16x8 r;
  r[0] = (short)f2b(lo[0]); r[1] = (short)f2b(lo[1]);
  r[2] = (short)f2b(lo[2]); r[3] = (short)f2b(lo[3]);
  r[4] = (short)f2b(hi[0]); r[5] = (short)f2b(hi[1]);
  r[6] = (short)f2b(hi[2]); r[7] = (short)f2b(hi[3]);
  return r;
}

// ------------- dtype detector: are inputs bf16 (flag=0) or fp32 (flag=1)? -------------
// Samples 4096 EVEN-indexed u16s of hidden_states. bf16 N(0,1) data: exponent byte
// in [0x70,0x8F] essentially always. fp32 data: even u16 = low mantissa half,
// ~uniform -> ~12.5% plausible. Threshold at 50%.
__global__ void detect_dtype(const u16* __restrict__ hs, u32* __restrict__ flag) {
  __shared__ u32 cnt;
  if (threadIdx.x == 0) cnt = 0;
  __syncthreads();
  int plaus = 0;
#pragma unroll
  for (int i = 0; i < 16; ++i) {
    u16 u = hs[(threadIdx.x * 16 + i) * 2];
    u32 e = (u >> 7) & 0xFF;
    if ((e >= 0x70 && e <= 0x8F) || (u & 0x7FFF) == 0) plaus++;
  }
  atomicAdd(&cnt, (u32)plaus);
  __syncthreads();
  if (threadIdx.x == 0) *flag = (cnt < 2048) ? 1u : 0u;
}

// ------------------- transpose (+convert) the 4 weight matrices -> bf16 -------------------
__global__ __launch_bounds__(256) void transpose_w(
    const void* __restrict__ w0, const void* __restrict__ w1,
    const void* __restrict__ w2, const void* __restrict__ w3,
    u16* __restrict__ out, const u32* __restrict__ flag)
{
  __shared__ u16 t[32][33];
  const bool isF32 = (*flag != 0);
  const void* src = blockIdx.z == 0 ? w0 : blockIdx.z == 1 ? w1 : blockIdx.z == 2 ? w2 : w3;
  u16* dst = out + (size_t)blockIdx.z * 409600;
  int tx = threadIdx.x, ty = threadIdx.y;
  int x = blockIdx.x * 32 + tx;
  int y = blockIdx.y * 32 + ty;
  if (isF32) {
    const float* s = (const float*)src;
#pragma unroll
    for (int j = 0; j < 32; j += 8) t[ty + j][tx] = f2b(s[(y + j) * D640 + x]);
  } else {
    const u16* s = (const u16*)src;
#pragma unroll
    for (int j = 0; j < 32; j += 8) t[ty + j][tx] = s[(y + j) * D640 + x];
  }
  __syncthreads();
  int x2 = blockIdx.y * 32 + tx;
  int y2 = blockIdx.x * 32 + ty;
#pragma unroll
  for (int j = 0; j < 32; j += 8) dst[(y2 + j) * D640 + x2] = t[tx][ty + j];
}

// ------------------- 128x128-tile bf16 GEMM: C = A @ (BT^T) -------------------
// A [*,640] (bf16, or fp32 if aF32mode&&flag), BT [640,640] bf16 row-major
// (BT[n][k]=B[k][n]), C [M,640] (bf16, or fp32 if cF32mode&&flag).
// aRow0: row offset into A. grid = (M/128, 5).
__global__ __launch_bounds__(256) void gemm_bt(
    const void* __restrict__ Av, const u16* __restrict__ BT, void* __restrict__ Cv,
    float scale, const void* __restrict__ bias, const u32* __restrict__ flag,
    int aRow0, int aF32mode, int cF32mode)
{
  __shared__ __align__(16) u16 Asub[128 * 32];
  __shared__ __align__(16) u16 Bsub[128 * 32];
  const bool isF32 = (*flag != 0);
  const bool aF32 = aF32mode && isF32;
  const bool cF32 = cF32mode && isF32;
  const int tid = threadIdx.x;
  const int lane = tid & 63, w = tid >> 6;
  const int wr = w >> 1, wc = w & 1;
  const int l15 = lane & 15, g = lane >> 4;
  const int rowBase = blockIdx.x * 128;
  const int colBase = blockIdx.y * 128;

  // thread covers global 16B(bf16-equivalent) chunks (r0, gc) and (r1, gc)
  const int r0 = tid >> 2, r1 = r0 + 64, gc = tid & 3;
  const int ls0 = r0 * 4 + (gc ^ ((r0 >> 1) & 3));
  const int ls1 = r1 * 4 + (gc ^ ((r1 >> 1) & 3));
  const size_t aIdx0 = (size_t)(aRow0 + rowBase + r0) * D640 + gc * 8;
  const size_t aIdx1 = (size_t)(aRow0 + rowBase + r1) * D640 + gc * 8;
  const u16* Bg0 = BT + (colBase + r0) * D640 + gc * 8;
  const u16* Bg1 = BT + (colBase + r1) * D640 + gc * 8;

  int aoff[4], boff[4];
#pragma unroll
  for (int f = 0; f < 4; ++f) {
    int R = wr * 64 + f * 16 + l15;
    aoff[f] = (R * 4 + (g ^ ((R >> 1) & 3))) * 8;
    int Cc = wc * 64 + f * 16 + l15;
    boff[f] = (Cc * 4 + (g ^ ((Cc >> 1) & 3))) * 8;
  }

  f32x4 acc[4][4];
#pragma unroll
  for (int i = 0; i < 4; ++i)
#pragma unroll
    for (int j = 0; j < 4; ++j) acc[i][j] = (f32x4){0.f, 0.f, 0.f, 0.f};

  for (int kt = 0; kt < 20; ++kt) {
    bf16x8 ra0, ra1;
    if (aF32) {
      const float* Af = (const float*)Av;
      const float* p0 = Af + aIdx0 + kt * 32;
      const float* p1 = Af + aIdx1 + kt * 32;
      ra0 = pack8(*(const f32x4*)p0, *(const f32x4*)(p0 + 4));
      ra1 = pack8(*(const f32x4*)p1, *(const f32x4*)(p1 + 4));
    } else {
      const u16* Ab = (const u16*)Av;
      ra0 = *(const bf16x8*)(Ab + aIdx0 + kt * 32);
      ra1 = *(const bf16x8*)(Ab + aIdx1 + kt * 32);
    }
    bf16x8 rb0 = *(const bf16x8*)(Bg0 + kt * 32);
    bf16x8 rb1 = *(const bf16x8*)(Bg1 + kt * 32);
    __syncthreads();
    *(bf16x8*)&Asub[ls0 * 8] = ra0;
    *(bf16x8*)&Asub[ls1 * 8] = ra1;
    *(bf16x8*)&Bsub[ls0 * 8] = rb0;
    *(bf16x8*)&Bsub[ls1 * 8] = rb1;
    __syncthreads();
    bf16x8 a[4], b[4];
#pragma unroll
    for (int f = 0; f < 4; ++f) a[f] = *(const bf16x8*)&Asub[aoff[f]];
#pragma unroll
    for (int f = 0; f < 4; ++f) b[f] = *(const bf16x8*)&Bsub[boff[f]];
#pragma unroll
    for (int i = 0; i < 4; ++i)
#pragma unroll
      for (int j = 0; j < 4; ++j)
        acc[i][j] = __builtin_amdgcn_mfma_f32_16x16x32_bf16(a[i], b[j], acc[i][j], 0, 0, 0);
  }

#pragma unroll
  for (int j = 0; j < 4; ++j) {
    int col = colBase + wc * 64 + j * 16 + l15;
    float bb = 0.f;
    if (bias) bb = cF32 ? ((const float*)bias)[col] : b2f(((const u16*)bias)[col]);
#pragma unroll
    for (int i = 0; i < 4; ++i) {
      int row = rowBase + wr * 64 + i * 16 + g * 4;
#pragma unroll
      for (int r = 0; r < 4; ++r) {
        float v = acc[i][j][r] * scale + bb;
        if (cF32) ((float*)Cv)[(size_t)(row + r) * D640 + col] = v;
        else      ((u16*)Cv)[(size_t)(row + r) * D640 + col] = f2b(v);
      }
    }
  }
}

// ------------------- flash attention (bf16 ws buffers only) -------------------
// grid = (16 qchunks, 128 frame*head). block = 256 (4 waves x 16 q-rows).
// Q prescaled by (1/sqrt(80))*log2(e) -> softmax in base-2.
__global__ __launch_bounds__(256) void attn_kernel(
    const u16* __restrict__ Q, const u16* __restrict__ K2,
    const u16* __restrict__ V2, u16* __restrict__ AO)
{
  __shared__ __align__(16) u16 Klds[32 * 104];   // padded stride 104, cols 80..95 stay 0
  __shared__ __align__(16) u16 VT[80 * 40];      // V transposed: VT[d][kk], stride 40
  __shared__ __align__(16) u16 Plds[4][640];     // per-wave P tile [16][40]

  const int tid = threadIdx.x, lane = tid & 63, w = tid >> 6;
  const int l15 = lane & 15, g = lane >> 4;
  const int qc = blockIdx.x, bh = blockIdx.y;
  const int f = bh >> 3, h = bh & 7;
  const int grp = f >> 3;

  const u16* Qp = Q + (f * 1024 + qc * 64 + w * 16) * D640 + h * 80;
  const u16* Kp = K2 + (grp * 1024) * D640 + h * 80;
  const u16* Vp = V2 + (grp * 1024) * D640 + h * 80;

  // defensive zero-init of ALL LDS
  {
    const bf16x8 z8 = {0, 0, 0, 0, 0, 0, 0, 0};
    u16* P0 = &Plds[0][0];
    for (int i = tid; i < 416; i += 256) *(bf16x8*)&Klds[i * 8] = z8;
    for (int i = tid; i < 400; i += 256) *(bf16x8*)&VT[i * 8] = z8;
    for (int i = tid; i < 320; i += 256) *(bf16x8*)&P0[i * 8] = z8;
  }

  const bf16x8 zz = {0, 0, 0, 0, 0, 0, 0, 0};
  bf16x8 qa[3];
#pragma unroll
  for (int i = 0; i < 3; ++i) {
    int kb = i * 32 + g * 8;
    qa[i] = (kb < 80) ? *(const bf16x8*)(Qp + l15 * D640 + kb) : zz;
  }

  f32x4 acc[5];
#pragma unroll
  for (int i = 0; i < 5; ++i) acc[i] = (f32x4){0.f, 0.f, 0.f, 0.f};
  float mrow[4] = {-1e30f, -1e30f, -1e30f, -1e30f};
  float lrow[4] = {0.f, 0.f, 0.f, 0.f};

  for (int it = 0; it < 32; ++it) {
    __syncthreads();
    {
      int t = tid, row = t / 10, c8 = t - row * 10;
      *(bf16x8*)&Klds[row * 104 + c8 * 8] =
          *(const bf16x8*)(Kp + (it * 32 + row) * D640 + c8 * 8);
    }
    if (tid < 64) {
      int t = tid + 256, row = t / 10, c8 = t - row * 10;
      *(bf16x8*)&Klds[row * 104 + c8 * 8] =
          *(const bf16x8*)(Kp + (it * 32 + row) * D640 + c8 * 8);
    }
#pragma unroll
    for (int i = 0; i < 5; ++i) {
      int e = tid + i * 256;
      int row = e / 40, c2 = e - row * 40;
      u32 vv = *(const u32*)(Vp + (it * 32 + row) * D640 + c2 * 2);
      VT[(c2 * 2) * 40 + row] = (u16)vv;
      VT[(c2 * 2 + 1) * 40 + row] = (u16)(vv >> 16);
    }
    __syncthreads();

    f32x4 s0 = {0.f, 0.f, 0.f, 0.f}, s1 = {0.f, 0.f, 0.f, 0.f};
#pragma unroll
    for (int i = 0; i < 3; ++i) {
      bf16x8 b0 = *(const bf16x8*)&Klds[l15 * 104 + i * 32 + g * 8];
      bf16x8 b1 = *(const bf16x8*)&Klds[(16 + l15) * 104 + i * 32 + g * 8];
      s0 = __builtin_amdgcn_mfma_f32_16x16x32_bf16(qa[i], b0, s0, 0, 0, 0);
      s1 = __builtin_amdgcn_mfma_f32_16x16x32_bf16(qa[i], b1, s1, 0, 0, 0);
    }

    float mt[4];
#pragma unroll
    for (int r = 0; r < 4; ++r) mt[r] = fmaxf(s0[r], s1[r]);
#pragma unroll
    for (int off = 1; off < 16; off <<= 1)
#pragma unroll
      for (int r = 0; r < 4; ++r) mt[r] = fmaxf(mt[r], __shfl_xor(mt[r], off, 64));

    float st[4], sc[4];
#pragma unroll
    for (int r = 0; r < 4; ++r) {
      float mn = fmaxf(mrow[r], mt[r]);
      sc[r] = exp2f(mrow[r] - mn);
      mrow[r] = mn;
      float p0 = exp2f(s0[r] - mn);
      float p1 = exp2f(s1[r] - mn);
      st[r] = p0 + p1;
      Plds[w][(g * 4 + r) * 40 + l15] = f2b(p0);
      Plds[w][(g * 4 + r) * 40 + 16 + l15] = f2b(p1);
    }
#pragma unroll
    for (int off = 1; off < 16; off <<= 1)
#pragma unroll
      for (int r = 0; r < 4; ++r) st[r] += __shfl_xor(st[r], off, 64);
#pragma unroll
    for (int r = 0; r < 4; ++r) lrow[r] = lrow[r] * sc[r] + st[r];
#pragma unroll
    for (int i = 0; i < 5; ++i)
#pragma unroll
      for (int r = 0; r < 4; ++r) acc[i][r] *= sc[r];

    bf16x8 pa = *(const bf16x8*)&Plds[w][l15 * 40 + g * 8];
#pragma unroll
    for (int i = 0; i < 5; ++i) {
      bf16x8 bv = *(const bf16x8*)&VT[(i * 16 + l15) * 40 + g * 8];
      acc[i] = __builtin_amdgcn_mfma_f32_16x16x32_bf16(pa, bv, acc[i], 0, 0, 0);
    }
  }

  u16* Op = AO + (f * 1024 + qc * 64 + w * 16) * D640 + h * 80;
#pragma unroll
  for (int r = 0; r < 4; ++r) {
    float inv = 1.f / lrow[r];
#pragma unroll
    for (int i = 0; i < 5; ++i)
      Op[(g * 4 + r) * D640 + i * 16 + l15] = f2b(acc[i][r] * inv);
  }
}

// ------------------- launcher -------------------
extern "C" void kernel_launch(void* const* d_in, const int* in_sizes, int n_in,
                              void* d_out, int out_size, void* d_ws, size_t ws_size,
                              hipStream_t stream) {
  (void)in_sizes; (void)n_in; (void)out_size; (void)ws_size;
  const void* hs = d_in[0];
  const void* wq = d_in[1];
  const void* wk = d_in[2];
  const void* wv = d_in[3];
  const void* wo = d_in[4];
  const void* bo = d_in[5];
  u16* ws = (u16*)d_ws;

  u16* WT  = ws;                         // 4 * 640*640         bf16
  u16* Qb  = ws + 1638400;               // 16384*640           bf16
  u16* Kb  = Qb + 10485760;              // 2048*640            bf16
  u16* Vb  = Kb + 1310720;               // 2048*640            bf16
  u16* AOb = Vb + 1310720;               // 16384*640           bf16
  u32* flag = (u32*)(AOb + 10485760);    // dtype flag

  const float QSCALE = 0.11180339887498949f * 1.44269504088896340f;

  detect_dtype<<<1, 256, 0, stream>>>((const u16*)hs, flag);

  transpose_w<<<dim3(20, 20, 4), dim3(32, 8), 0, stream>>>(wq, wk, wv, wo, WT, flag);

  // Q projection (all 16384 rows)
  gemm_bt<<<dim3(128, 5), 256, 0, stream>>>(hs, WT, Qb, QSCALE, nullptr, flag, 0, 1, 0);
  // K/V only for the first frame of each batch group (frames 0 and 8)
  gemm_bt<<<dim3(8, 5), 256, 0, stream>>>(hs, WT + 409600, Kb,              1.f, nullptr, flag, 0,    1, 0);
  gemm_bt<<<dim3(8, 5), 256, 0, stream>>>(hs, WT + 409600, Kb + 1024 * 640, 1.f, nullptr, flag, 8192, 1, 0);
  gemm_bt<<<dim3(8, 5), 256, 0, stream>>>(hs, WT + 819200, Vb,              1.f, nullptr, flag, 0,    1, 0);
  gemm_bt<<<dim3(8, 5), 256, 0, stream>>>(hs, WT + 819200, Vb + 1024 * 640, 1.f, nullptr, flag, 8192, 1, 0);

  attn_kernel<<<dim3(16, 128), 256, 0, stream>>>(Qb, Kb, Vb, AOb);

  // output projection + bias; C dtype follows detected input dtype
  gemm_bt<<<dim3(128, 5), 256, 0, stream>>>(AOb, WT + 1228800, d_out, 1.f, bo, flag, 0, 0, 1);
}

// Round 4
// 249.482 us; speedup vs baseline: 1.4907x; 1.4907x over previous
//
#include <hip/hip_runtime.h>

typedef unsigned short u16;
typedef unsigned int u32;
typedef __attribute__((ext_vector_type(8))) short bf16x8;
typedef __attribute__((ext_vector_type(4))) float f32x4;

#define D640 640

__device__ __forceinline__ float b2f(u16 u) {
  union { u32 i; float f; } x; x.i = ((u32)u) << 16; return x.f;
}
__device__ __forceinline__ u16 f2b(float f) {
  union { float f; u32 i; } x; x.f = f;
  u32 r = x.i + 0x7FFFu + ((x.i >> 16) & 1u);
  return (u16)(r >> 16);
}
__device__ __forceinline__ bf16x8 pack8(f32x4 lo, f32x4 hi) {
  bf16x8 r;
  r[0] = (short)f2b(lo[0]); r[1] = (short)f2b(lo[1]);
  r[2] = (short)f2b(lo[2]); r[3] = (short)f2b(lo[3]);
  r[4] = (short)f2b(hi[0]); r[5] = (short)f2b(hi[1]);
  r[6] = (short)f2b(hi[2]); r[7] = (short)f2b(hi[3]);
  return r;
}
__device__ __forceinline__ u32 pack2(float a, float b) {
  return (u32)f2b(a) | ((u32)f2b(b) << 16);
}

// ------------- dtype detector: inputs bf16 (flag=0) or fp32 (flag=1)? -------------
__global__ void detect_dtype(const u16* __restrict__ hs, u32* __restrict__ flag) {
  __shared__ u32 cnt;
  if (threadIdx.x == 0) cnt = 0;
  __syncthreads();
  int plaus = 0;
#pragma unroll
  for (int i = 0; i < 16; ++i) {
    u16 u = hs[(threadIdx.x * 16 + i) * 2];
    u32 e = (u >> 7) & 0xFF;
    if ((e >= 0x70 && e <= 0x8F) || (u & 0x7FFF) == 0) plaus++;
  }
  atomicAdd(&cnt, (u32)plaus);
  __syncthreads();
  if (threadIdx.x == 0) *flag = (cnt < 2048) ? 1u : 0u;
}

// ------------------- transpose (+convert) the 4 weight matrices -> bf16 -------------------
__global__ __launch_bounds__(256) void transpose_w(
    const void* __restrict__ w0, const void* __restrict__ w1,
    const void* __restrict__ w2, const void* __restrict__ w3,
    u16* __restrict__ out, const u32* __restrict__ flag)
{
  __shared__ u16 t[32][33];
  const bool isF32 = (*flag != 0);
  const void* src = blockIdx.z == 0 ? w0 : blockIdx.z == 1 ? w1 : blockIdx.z == 2 ? w2 : w3;
  u16* dst = out + (size_t)blockIdx.z * 409600;
  int tx = threadIdx.x, ty = threadIdx.y;
  int x = blockIdx.x * 32 + tx;
  int y = blockIdx.y * 32 + ty;
  if (isF32) {
    const float* s = (const float*)src;
#pragma unroll
    for (int j = 0; j < 32; j += 8) t[ty + j][tx] = f2b(s[(y + j) * D640 + x]);
  } else {
    const u16* s = (const u16*)src;
#pragma unroll
    for (int j = 0; j < 32; j += 8) t[ty + j][tx] = s[(y + j) * D640 + x];
  }
  __syncthreads();
  int x2 = blockIdx.y * 32 + tx;
  int y2 = blockIdx.x * 32 + ty;
#pragma unroll
  for (int j = 0; j < 32; j += 8) dst[(y2 + j) * D640 + x2] = t[tx][ty + j];
}

// ------------------- 128x128-tile bf16 GEMM: C = A @ (BT^T) -------------------
// cMode: 0 = bf16 store [row][640];  1 = fp32-if-flag store [row][640];
//        2 = bf16 V^T store: Cv[(size_t)col*1024 + row]  (per-group base passed in)
__global__ __launch_bounds__(256) void gemm_bt(
    const void* __restrict__ Av, const u16* __restrict__ BT, void* __restrict__ Cv,
    float scale, const void* __restrict__ bias, const u32* __restrict__ flag,
    int aRow0, int aF32mode, int cMode)
{
  __shared__ __align__(16) u16 Asub[128 * 32];
  __shared__ __align__(16) u16 Bsub[128 * 32];
  const bool isF32 = (*flag != 0);
  const bool aF32 = aF32mode && isF32;
  const bool cF32 = (cMode == 1) && isF32;
  const int tid = threadIdx.x;
  const int lane = tid & 63, w = tid >> 6;
  const int wr = w >> 1, wc = w & 1;
  const int l15 = lane & 15, g = lane >> 4;
  const int rowBase = blockIdx.x * 128;
  const int colBase = blockIdx.y * 128;

  const int r0 = tid >> 2, r1 = r0 + 64, gc = tid & 3;
  const int ls0 = r0 * 4 + (gc ^ ((r0 >> 1) & 3));
  const int ls1 = r1 * 4 + (gc ^ ((r1 >> 1) & 3));
  const size_t aIdx0 = (size_t)(aRow0 + rowBase + r0) * D640 + gc * 8;
  const size_t aIdx1 = (size_t)(aRow0 + rowBase + r1) * D640 + gc * 8;
  const u16* Bg0 = BT + (colBase + r0) * D640 + gc * 8;
  const u16* Bg1 = BT + (colBase + r1) * D640 + gc * 8;

  int aoff[4], boff[4];
#pragma unroll
  for (int f = 0; f < 4; ++f) {
    int R = wr * 64 + f * 16 + l15;
    aoff[f] = (R * 4 + (g ^ ((R >> 1) & 3))) * 8;
    int Cc = wc * 64 + f * 16 + l15;
    boff[f] = (Cc * 4 + (g ^ ((Cc >> 1) & 3))) * 8;
  }

  f32x4 acc[4][4];
#pragma unroll
  for (int i = 0; i < 4; ++i)
#pragma unroll
    for (int j = 0; j < 4; ++j) acc[i][j] = (f32x4){0.f, 0.f, 0.f, 0.f};

  for (int kt = 0; kt < 20; ++kt) {
    bf16x8 ra0, ra1;
    if (aF32) {
      const float* Af = (const float*)Av;
      const float* p0 = Af + aIdx0 + kt * 32;
      const float* p1 = Af + aIdx1 + kt * 32;
      ra0 = pack8(*(const f32x4*)p0, *(const f32x4*)(p0 + 4));
      ra1 = pack8(*(const f32x4*)p1, *(const f32x4*)(p1 + 4));
    } else {
      const u16* Ab = (const u16*)Av;
      ra0 = *(const bf16x8*)(Ab + aIdx0 + kt * 32);
      ra1 = *(const bf16x8*)(Ab + aIdx1 + kt * 32);
    }
    bf16x8 rb0 = *(const bf16x8*)(Bg0 + kt * 32);
    bf16x8 rb1 = *(const bf16x8*)(Bg1 + kt * 32);
    __syncthreads();
    *(bf16x8*)&Asub[ls0 * 8] = ra0;
    *(bf16x8*)&Asub[ls1 * 8] = ra1;
    *(bf16x8*)&Bsub[ls0 * 8] = rb0;
    *(bf16x8*)&Bsub[ls1 * 8] = rb1;
    __syncthreads();
    bf16x8 a[4], b[4];
#pragma unroll
    for (int f = 0; f < 4; ++f) a[f] = *(const bf16x8*)&Asub[aoff[f]];
#pragma unroll
    for (int f = 0; f < 4; ++f) b[f] = *(const bf16x8*)&Bsub[boff[f]];
#pragma unroll
    for (int i = 0; i < 4; ++i)
#pragma unroll
      for (int j = 0; j < 4; ++j)
        acc[i][j] = __builtin_amdgcn_mfma_f32_16x16x32_bf16(a[i], b[j], acc[i][j], 0, 0, 0);
  }

#pragma unroll
  for (int j = 0; j < 4; ++j) {
    int col = colBase + wc * 64 + j * 16 + l15;
    float bb = 0.f;
    if (bias) bb = cF32 ? ((const float*)bias)[col] : b2f(((const u16*)bias)[col]);
#pragma unroll
    for (int i = 0; i < 4; ++i) {
      int row = rowBase + wr * 64 + i * 16 + g * 4;
#pragma unroll
      for (int r = 0; r < 4; ++r) {
        float v = acc[i][j][r] * scale + bb;
        if (cMode == 2)       ((u16*)Cv)[(size_t)col * 1024 + (row + r)] = f2b(v);
        else if (cF32)        ((float*)Cv)[(size_t)(row + r) * D640 + col] = v;
        else                  ((u16*)Cv)[(size_t)(row + r) * D640 + col] = f2b(v);
      }
    }
  }
}

// ------------------- flash attention v2 -------------------
// grid = (8 qchunks, 128 frame*head). block = 256 (4 waves x 32 q-rows).
// KVBLK = 64, swapped QK^T (S^T lane-local per q), defer-max, reg-prefetch staging.
// V pre-transposed in global: VT[(grp*8+h)*80*1024 + d*1024 + key].
__global__ __launch_bounds__(256, 3) void attn_kernel(
    const u16* __restrict__ Q, const u16* __restrict__ K2,
    const u16* __restrict__ VT, u16* __restrict__ AO)
{
  __shared__ __align__(16) u16 Klds[64 * 104];     // keys x d (pad 80..95 zero)
  __shared__ __align__(16) u16 Vlds[80 * 72];      // d x keys (stride 72)
  __shared__ __align__(16) u16 Plds[4][32 * 72];   // per-wave P [q=32][key=64] stride 72

  const int tid = threadIdx.x, lane = tid & 63, w = tid >> 6;
  const int l15 = lane & 15, g = lane >> 4;
  const int qc = blockIdx.x, bh = blockIdx.y;
  const int f = bh >> 3, h = bh & 7;
  const int grp = f >> 3;

  const u16* Qp = Q + (size_t)(f * 1024 + qc * 128 + w * 32) * D640 + h * 80;
  const u16* Kp = K2 + (size_t)(grp * 1024) * D640 + h * 80;
  const u16* Vp = VT + (size_t)(grp * 8 + h) * 80 * 1024;

  // zero K pad cols 80..95 (staging never writes them)
  if (tid < 128) {
    const bf16x8 z8 = {0, 0, 0, 0, 0, 0, 0, 0};
    *(bf16x8*)&Klds[(tid >> 1) * 104 + 80 + (tid & 1) * 8] = z8;
  }

  // Q fragments: [qb=2][dc=3], lane holds Q[q=l15+16qb][dc*32+g*8 .. +7], 0 past d=80
  bf16x8 qreg[2][3];
#pragma unroll
  for (int qb = 0; qb < 2; ++qb)
#pragma unroll
    for (int dc = 0; dc < 3; ++dc) {
      int dd = dc * 32 + g * 8;
      if (dd < 80) qreg[qb][dc] = *(const bf16x8*)(Qp + (l15 + 16 * qb) * D640 + dd);
      else         qreg[qb][dc] = (bf16x8){0, 0, 0, 0, 0, 0, 0, 0};
    }

  f32x4 acc[2][5];
#pragma unroll
  for (int qb = 0; qb < 2; ++qb)
#pragma unroll
    for (int db = 0; db < 5; ++db) acc[qb][db] = (f32x4){0.f, 0.f, 0.f, 0.f};
  float mreg[2] = {-1e30f, -1e30f};
  float lrow[2] = {0.f, 0.f};

  // staging: 1280 16B chunks (640 K + 640 V), 5 per thread
  const u16* gsrc[5];
  u16* ldst[5];
  int step[5];
#pragma unroll
  for (int i = 0; i < 5; ++i) {
    int c = tid + i * 256;
    if (c < 640) {
      int row = c / 10, cc = c - row * 10;
      gsrc[i] = Kp + row * D640 + cc * 8;
      ldst[i] = &Klds[row * 104 + cc * 8];
      step[i] = 64 * D640;
    } else {
      int c2 = c - 640, d = c2 >> 3, cc = c2 & 7;
      gsrc[i] = Vp + d * 1024 + cc * 8;
      ldst[i] = &Vlds[d * 72 + cc * 8];
      step[i] = 64;
    }
  }

  bf16x8 pre[5];
#pragma unroll
  for (int i = 0; i < 5; ++i) pre[i] = *(const bf16x8*)gsrc[i];

  for (int it = 0; it < 16; ++it) {
    __syncthreads();
#pragma unroll
    for (int i = 0; i < 5; ++i) *(bf16x8*)ldst[i] = pre[i];
    __syncthreads();
    if (it < 15) {
#pragma unroll
      for (int i = 0; i < 5; ++i) pre[i] = *(const bf16x8*)(gsrc[i] + (it + 1) * step[i]);
    }

    // QK^T (swapped): st[kb][qb] = S^T fragment; lane: q=l15+16qb, keys kb*16+g*4+r
    f32x4 st[4][2];
#pragma unroll
    for (int kb = 0; kb < 4; ++kb)
#pragma unroll
      for (int qb = 0; qb < 2; ++qb) st[kb][qb] = (f32x4){0.f, 0.f, 0.f, 0.f};
#pragma unroll
    for (int dc = 0; dc < 3; ++dc)
#pragma unroll
      for (int kb = 0; kb < 4; ++kb) {
        bf16x8 ka = *(const bf16x8*)&Klds[(kb * 16 + l15) * 104 + dc * 32 + g * 8];
        st[kb][0] = __builtin_amdgcn_mfma_f32_16x16x32_bf16(ka, qreg[0][dc], st[kb][0], 0, 0, 0);
        st[kb][1] = __builtin_amdgcn_mfma_f32_16x16x32_bf16(ka, qreg[1][dc], st[kb][1], 0, 0, 0);
      }

    // tile max per qb (in-register over 16, then reduce across g-groups)
    float mt[2];
#pragma unroll
    for (int qb = 0; qb < 2; ++qb) {
      float m01 = fmaxf(fmaxf(st[0][qb][0], st[0][qb][1]), fmaxf(st[0][qb][2], st[0][qb][3]));
      float m23 = fmaxf(fmaxf(st[1][qb][0], st[1][qb][1]), fmaxf(st[1][qb][2], st[1][qb][3]));
      float m45 = fmaxf(fmaxf(st[2][qb][0], st[2][qb][1]), fmaxf(st[2][qb][2], st[2][qb][3]));
      float m67 = fmaxf(fmaxf(st[3][qb][0], st[3][qb][1]), fmaxf(st[3][qb][2], st[3][qb][3]));
      float m = fmaxf(fmaxf(m01, m23), fmaxf(m45, m67));
      m = fmaxf(m, __shfl_xor(m, 16, 64));
      m = fmaxf(m, __shfl_xor(m, 32, 64));
      mt[qb] = m;
    }

    // defer-max rescale (rare)
    if (__any((mt[0] > mreg[0] + 8.f) || (mt[1] > mreg[1] + 8.f))) {
#pragma unroll
      for (int qb = 0; qb < 2; ++qb) {
        float mn = fmaxf(mreg[qb], mt[qb]);
        float scl = exp2f(mreg[qb] - mn);
        mreg[qb] = mn;
        lrow[qb] *= scl;
        float s_[4];
#pragma unroll
        for (int r = 0; r < 4; ++r)
          s_[r] = __shfl(scl, (lane & 48) | (g * 4 + r), 64);
#pragma unroll
        for (int db = 0; db < 5; ++db)
#pragma unroll
          for (int r = 0; r < 4; ++r) acc[qb][db][r] *= s_[r];
      }
    }

    // P = exp2(S^T - m), accumulate l, pack to bf16, store to per-wave P LDS
#pragma unroll
    for (int qb = 0; qb < 2; ++qb) {
      float sum = 0.f;
#pragma unroll
      for (int kb = 0; kb < 4; ++kb) {
        float p0 = exp2f(st[kb][qb][0] - mreg[qb]);
        float p1 = exp2f(st[kb][qb][1] - mreg[qb]);
        float p2 = exp2f(st[kb][qb][2] - mreg[qb]);
        float p3 = exp2f(st[kb][qb][3] - mreg[qb]);
        sum += (p0 + p1) + (p2 + p3);
        uint2 pk;
        pk.x = pack2(p0, p1);
        pk.y = pack2(p2, p3);
        *(uint2*)&Plds[w][(l15 + 16 * qb) * 72 + kb * 16 + g * 4] = pk;
      }
      sum += __shfl_xor(sum, 16, 64);
      sum += __shfl_xor(sum, 32, 64);
      lrow[qb] += sum;
    }

    // PV: O[q][d] += P[q][keys] * V^T[d][keys]
#pragma unroll
    for (int kc = 0; kc < 2; ++kc) {
      bf16x8 pa0 = *(const bf16x8*)&Plds[w][(l15) * 72 + kc * 32 + g * 8];
      bf16x8 pa1 = *(const bf16x8*)&Plds[w][(l15 + 16) * 72 + kc * 32 + g * 8];
#pragma unroll
      for (int db = 0; db < 5; ++db) {
        bf16x8 bv = *(const bf16x8*)&Vlds[(db * 16 + l15) * 72 + kc * 32 + g * 8];
        acc[0][db] = __builtin_amdgcn_mfma_f32_16x16x32_bf16(pa0, bv, acc[0][db], 0, 0, 0);
        acc[1][db] = __builtin_amdgcn_mfma_f32_16x16x32_bf16(pa1, bv, acc[1][db], 0, 0, 0);
      }
    }
  }

  // epilogue: O rows q = qb*16 + g*4 + r, cols d = db*16 + l15
  u16* Op = AO + (size_t)(f * 1024 + qc * 128 + w * 32) * D640 + h * 80;
#pragma unroll
  for (int qb = 0; qb < 2; ++qb) {
    float i_[4];
#pragma unroll
    for (int r = 0; r < 4; ++r)
      i_[r] = 1.f / __shfl(lrow[qb], (lane & 48) | (g * 4 + r), 64);
#pragma unroll
    for (int db = 0; db < 5; ++db)
#pragma unroll
      for (int r = 0; r < 4; ++r)
        Op[(qb * 16 + g * 4 + r) * D640 + db * 16 + l15] = f2b(acc[qb][db][r] * i_[r]);
  }
}

// ------------------- launcher -------------------
extern "C" void kernel_launch(void* const* d_in, const int* in_sizes, int n_in,
                              void* d_out, int out_size, void* d_ws, size_t ws_size,
                              hipStream_t stream) {
  (void)in_sizes; (void)n_in; (void)out_size; (void)ws_size;
  const void* hs = d_in[0];
  const void* wq = d_in[1];
  const void* wk = d_in[2];
  const void* wv = d_in[3];
  const void* wo = d_in[4];
  const void* bo = d_in[5];
  u16* ws = (u16*)d_ws;

  u16* WT  = ws;                         // 4 * 640*640         bf16
  u16* Qb  = ws + 1638400;               // 16384*640           bf16
  u16* Kb  = Qb + 10485760;              // 2048*640            bf16
  u16* Vb  = Kb + 1310720;               // V^T: 2 grp x [640 col][1024 key]
  u16* AOb = Vb + 1310720;               // 16384*640           bf16
  u32* flag = (u32*)(AOb + 10485760);    // dtype flag

  const float QSCALE = 0.11180339887498949f * 1.44269504088896340f;

  detect_dtype<<<1, 256, 0, stream>>>((const u16*)hs, flag);

  transpose_w<<<dim3(20, 20, 4), dim3(32, 8), 0, stream>>>(wq, wk, wv, wo, WT, flag);

  // Q projection (all 16384 rows), scale folded in
  gemm_bt<<<dim3(128, 5), 256, 0, stream>>>(hs, WT, Qb, QSCALE, nullptr, flag, 0, 1, 0);
  // K for frames 0 and 8 (first of each batch group)
  gemm_bt<<<dim3(8, 5), 256, 0, stream>>>(hs, WT + 409600, Kb,              1.f, nullptr, flag, 0,    1, 0);
  gemm_bt<<<dim3(8, 5), 256, 0, stream>>>(hs, WT + 409600, Kb + 1024 * 640, 1.f, nullptr, flag, 8192, 1, 0);
  // V for frames 0 and 8, stored TRANSPOSED (cMode=2): Vb[grp][col*1024 + key]
  gemm_bt<<<dim3(8, 5), 256, 0, stream>>>(hs, WT + 819200, Vb,          1.f, nullptr, flag, 0,    1, 2);
  gemm_bt<<<dim3(8, 5), 256, 0, stream>>>(hs, WT + 819200, Vb + 655360, 1.f, nullptr, flag, 8192, 1, 2);

  attn_kernel<<<dim3(8, 128), 256, 0, stream>>>(Qb, Kb, Vb, AOb);

  // output projection + bias; C dtype follows detected input dtype
  gemm_bt<<<dim3(128, 5), 256, 0, stream>>>(AOb, WT + 1228800, d_out, 1.f, bo, flag, 0, 0, 1);
}

// Round 5
// 172.564 us; speedup vs baseline: 2.1552x; 1.4457x over previous
//
#include <hip/hip_runtime.h>
#include <hip/hip_bf16.h>

typedef unsigned short u16;
typedef unsigned int u32;
typedef __attribute__((ext_vector_type(8))) short bf16x8;
typedef __attribute__((ext_vector_type(4))) float f32x4;

#define D640 640

__device__ __forceinline__ float b2f(u16 u) {
  union { u32 i; float f; } x; x.i = ((u32)u) << 16; return x.f;
}
// native cast -> compiler emits v_cvt_pk_bf16_f32 (RNE), m240: don't hand-roll
__device__ __forceinline__ u16 f2b(float f) {
  union { __hip_bfloat16 h; u16 u; } c; c.h = __float2bfloat16(f); return c.u;
}
__device__ __forceinline__ u32 pack2(float a, float b) {
  union { __hip_bfloat162 h; u32 u; } c;
  c.h.x = __float2bfloat16(a); c.h.y = __float2bfloat16(b); return c.u;
}
__device__ __forceinline__ bf16x8 pack8(f32x4 lo, f32x4 hi) {
  bf16x8 r;
  r[0] = (short)f2b(lo[0]); r[1] = (short)f2b(lo[1]);
  r[2] = (short)f2b(lo[2]); r[3] = (short)f2b(lo[3]);
  r[4] = (short)f2b(hi[0]); r[5] = (short)f2b(hi[1]);
  r[6] = (short)f2b(hi[2]); r[7] = (short)f2b(hi[3]);
  return r;
}

// ------------- dtype detector: inputs bf16 (flag=0) or fp32 (flag=1)? -------------
__global__ void detect_dtype(const u16* __restrict__ hs, u32* __restrict__ flag) {
  __shared__ u32 cnt;
  if (threadIdx.x == 0) cnt = 0;
  __syncthreads();
  int plaus = 0;
#pragma unroll
  for (int i = 0; i < 16; ++i) {
    u16 u = hs[(threadIdx.x * 16 + i) * 2];
    u32 e = (u >> 7) & 0xFF;
    if ((e >= 0x70 && e <= 0x8F) || (u & 0x7FFF) == 0) plaus++;
  }
  atomicAdd(&cnt, (u32)plaus);
  __syncthreads();
  if (threadIdx.x == 0) *flag = (cnt < 2048) ? 1u : 0u;
}

// ------------------- transpose (+convert) the 4 weight matrices -> bf16 -------------------
__global__ __launch_bounds__(256) void transpose_w(
    const void* __restrict__ w0, const void* __restrict__ w1,
    const void* __restrict__ w2, const void* __restrict__ w3,
    u16* __restrict__ out, const u32* __restrict__ flag)
{
  __shared__ u16 t[32][33];
  const bool isF32 = (*flag != 0);
  const void* src = blockIdx.z == 0 ? w0 : blockIdx.z == 1 ? w1 : blockIdx.z == 2 ? w2 : w3;
  u16* dst = out + (size_t)blockIdx.z * 409600;
  int tx = threadIdx.x, ty = threadIdx.y;
  int x = blockIdx.x * 32 + tx;
  int y = blockIdx.y * 32 + ty;
  if (isF32) {
    const float* s = (const float*)src;
#pragma unroll
    for (int j = 0; j < 32; j += 8) t[ty + j][tx] = f2b(s[(y + j) * D640 + x]);
  } else {
    const u16* s = (const u16*)src;
#pragma unroll
    for (int j = 0; j < 32; j += 8) t[ty + j][tx] = s[(y + j) * D640 + x];
  }
  __syncthreads();
  int x2 = blockIdx.y * 32 + tx;
  int y2 = blockIdx.x * 32 + ty;
#pragma unroll
  for (int j = 0; j < 32; j += 8) dst[(y2 + j) * D640 + x2] = t[tx][ty + j];
}

// ------------------- 128x128-tile bf16 GEMM body: C = A @ (BT^T) -------------------
// cMode: 0 bf16 [row][640]; 1 fp32-if-flag [row][640]; 2 bf16 V^T [col*1024+row]
__device__ __forceinline__ void gemm_body(
    const void* __restrict__ Av, const u16* __restrict__ BT, void* __restrict__ Cv,
    float scale, const void* __restrict__ bias, bool isF32,
    int aRow0, int aF32mode, int cMode, int bx, int by)
{
  __shared__ __align__(16) u16 Asub[128 * 32];
  __shared__ __align__(16) u16 Bsub[128 * 32];
  const bool aF32 = aF32mode && isF32;
  const bool cF32 = (cMode == 1) && isF32;
  const int tid = threadIdx.x;
  const int lane = tid & 63, w = tid >> 6;
  const int wr = w >> 1, wc = w & 1;
  const int l15 = lane & 15, g = lane >> 4;
  const int rowBase = bx * 128;
  const int colBase = by * 128;

  const int r0 = tid >> 2, r1 = r0 + 64, gc = tid & 3;
  const int ls0 = r0 * 4 + (gc ^ ((r0 >> 1) & 3));
  const int ls1 = r1 * 4 + (gc ^ ((r1 >> 1) & 3));
  const size_t aIdx0 = (size_t)(aRow0 + rowBase + r0) * D640 + gc * 8;
  const size_t aIdx1 = (size_t)(aRow0 + rowBase + r1) * D640 + gc * 8;
  const u16* Bg0 = BT + (colBase + r0) * D640 + gc * 8;
  const u16* Bg1 = BT + (colBase + r1) * D640 + gc * 8;

  int aoff[4], boff[4];
#pragma unroll
  for (int f = 0; f < 4; ++f) {
    int R = wr * 64 + f * 16 + l15;
    aoff[f] = (R * 4 + (g ^ ((R >> 1) & 3))) * 8;
    int Cc = wc * 64 + f * 16 + l15;
    boff[f] = (Cc * 4 + (g ^ ((Cc >> 1) & 3))) * 8;
  }

  f32x4 acc[4][4];
#pragma unroll
  for (int i = 0; i < 4; ++i)
#pragma unroll
    for (int j = 0; j < 4; ++j) acc[i][j] = (f32x4){0.f, 0.f, 0.f, 0.f};

  bf16x8 ra0, ra1, rb0, rb1;
  // prefetch tile 0
  if (aF32) {
    const float* Af = (const float*)Av;
    ra0 = pack8(*(const f32x4*)(Af + aIdx0), *(const f32x4*)(Af + aIdx0 + 4));
    ra1 = pack8(*(const f32x4*)(Af + aIdx1), *(const f32x4*)(Af + aIdx1 + 4));
  } else {
    const u16* Ab = (const u16*)Av;
    ra0 = *(const bf16x8*)(Ab + aIdx0);
    ra1 = *(const bf16x8*)(Ab + aIdx1);
  }
  rb0 = *(const bf16x8*)Bg0;
  rb1 = *(const bf16x8*)Bg1;

  for (int kt = 0; kt < 20; ++kt) {
    __syncthreads();
    *(bf16x8*)&Asub[ls0 * 8] = ra0;
    *(bf16x8*)&Asub[ls1 * 8] = ra1;
    *(bf16x8*)&Bsub[ls0 * 8] = rb0;
    *(bf16x8*)&Bsub[ls1 * 8] = rb1;
    __syncthreads();
    // issue next-tile global loads NOW; they fly under the MFMAs (T3-minimal)
    if (kt < 19) {
      const int k1 = (kt + 1) * 32;
      if (aF32) {
        const float* Af = (const float*)Av;
        ra0 = pack8(*(const f32x4*)(Af + aIdx0 + k1), *(const f32x4*)(Af + aIdx0 + k1 + 4));
        ra1 = pack8(*(const f32x4*)(Af + aIdx1 + k1), *(const f32x4*)(Af + aIdx1 + k1 + 4));
      } else {
        const u16* Ab = (const u16*)Av;
        ra0 = *(const bf16x8*)(Ab + aIdx0 + k1);
        ra1 = *(const bf16x8*)(Ab + aIdx1 + k1);
      }
      rb0 = *(const bf16x8*)(Bg0 + k1);
      rb1 = *(const bf16x8*)(Bg1 + k1);
    }
    bf16x8 a[4], b[4];
#pragma unroll
    for (int f = 0; f < 4; ++f) a[f] = *(const bf16x8*)&Asub[aoff[f]];
#pragma unroll
    for (int f = 0; f < 4; ++f) b[f] = *(const bf16x8*)&Bsub[boff[f]];
    __builtin_amdgcn_s_setprio(1);
#pragma unroll
    for (int i = 0; i < 4; ++i)
#pragma unroll
      for (int j = 0; j < 4; ++j)
        acc[i][j] = __builtin_amdgcn_mfma_f32_16x16x32_bf16(a[i], b[j], acc[i][j], 0, 0, 0);
    __builtin_amdgcn_s_setprio(0);
  }

#pragma unroll
  for (int j = 0; j < 4; ++j) {
    int col = colBase + wc * 64 + j * 16 + l15;
    float bb = 0.f;
    if (bias) bb = cF32 ? ((const float*)bias)[col] : b2f(((const u16*)bias)[col]);
#pragma unroll
    for (int i = 0; i < 4; ++i) {
      int row = rowBase + wr * 64 + i * 16 + g * 4;
#pragma unroll
      for (int r = 0; r < 4; ++r) {
        float v = acc[i][j][r] * scale + bb;
        if (cMode == 2)       ((u16*)Cv)[(size_t)col * 1024 + (row + r)] = f2b(v);
        else if (cF32)        ((float*)Cv)[(size_t)(row + r) * D640 + col] = v;
        else                  ((u16*)Cv)[(size_t)(row + r) * D640 + col] = f2b(v);
      }
    }
  }
}

__global__ __launch_bounds__(256) void gemm_bt(
    const void* __restrict__ Av, const u16* __restrict__ BT, void* __restrict__ Cv,
    float scale, const void* __restrict__ bias, const u32* __restrict__ flag,
    int aRow0, int aF32mode, int cMode)
{
  gemm_body(Av, BT, Cv, scale, bias, (*flag != 0), aRow0, aF32mode, cMode,
            blockIdx.x, blockIdx.y);
}

// merged K/V projection: z = 0: K grp0, 1: K grp1, 2: V grp0 (V^T), 3: V grp1 (V^T)
__global__ __launch_bounds__(256) void gemm_kv(
    const void* __restrict__ hs, const u16* __restrict__ WTk, const u16* __restrict__ WTv,
    u16* __restrict__ Kb, u16* __restrict__ Vb, const u32* __restrict__ flag)
{
  const int z = blockIdx.z;
  const bool isK = (z < 2);
  const int grp = z & 1;
  const u16* bt = isK ? WTk : WTv;
  void* cv = isK ? (void*)(Kb + (size_t)grp * 1024 * 640)
                 : (void*)(Vb + (size_t)grp * 655360);
  gemm_body(hs, bt, cv, 1.f, nullptr, (*flag != 0), grp * 8192, 1, isK ? 0 : 2,
            blockIdx.x, blockIdx.y);
}

// ------------------- flash attention v2 -------------------
// grid = (8 qchunks, 128 frame*head). block = 256 (4 waves x 32 q-rows).
// KVBLK = 64, swapped QK^T (S^T lane-local per q), defer-max, reg-prefetch staging.
// V pre-transposed in global: VT[(grp*8+h)*80*1024 + d*1024 + key].
__global__ __launch_bounds__(256, 3) void attn_kernel(
    const u16* __restrict__ Q, const u16* __restrict__ K2,
    const u16* __restrict__ VT, u16* __restrict__ AO)
{
  __shared__ __align__(16) u16 Klds[64 * 104];     // keys x d (pad 80..95 zero)
  __shared__ __align__(16) u16 Vlds[80 * 72];      // d x keys (stride 72)
  __shared__ __align__(16) u16 Plds[4][32 * 72];   // per-wave P [q=32][key=64] stride 72

  const int tid = threadIdx.x, lane = tid & 63, w = tid >> 6;
  const int l15 = lane & 15, g = lane >> 4;
  const int qc = blockIdx.x, bh = blockIdx.y;
  const int f = bh >> 3, h = bh & 7;
  const int grp = f >> 3;
  u16* Pw = &Plds[w][0];

  const u16* Qp = Q + (size_t)(f * 1024 + qc * 128 + w * 32) * D640 + h * 80;
  const u16* Kp = K2 + (size_t)(grp * 1024) * D640 + h * 80;
  const u16* Vp = VT + (size_t)(grp * 8 + h) * 80 * 1024;

  // zero K pad cols 80..95 (staging never writes them; NaN*0=NaN so must be 0)
  if (tid < 128) {
    const bf16x8 z8 = {0, 0, 0, 0, 0, 0, 0, 0};
    *(bf16x8*)&Klds[(tid >> 1) * 104 + 80 + (tid & 1) * 8] = z8;
  }

  // Q fragments: [qb=2][dc=3], lane holds Q[q=l15+16qb][dc*32+g*8 .. +7], 0 past d=80
  bf16x8 qreg[2][3];
#pragma unroll
  for (int qb = 0; qb < 2; ++qb)
#pragma unroll
    for (int dc = 0; dc < 3; ++dc) {
      int dd = dc * 32 + g * 8;
      if (dd < 80) qreg[qb][dc] = *(const bf16x8*)(Qp + (l15 + 16 * qb) * D640 + dd);
      else         qreg[qb][dc] = (bf16x8){0, 0, 0, 0, 0, 0, 0, 0};
    }

  f32x4 acc[2][5];
#pragma unroll
  for (int qb = 0; qb < 2; ++qb)
#pragma unroll
    for (int db = 0; db < 5; ++db) acc[qb][db] = (f32x4){0.f, 0.f, 0.f, 0.f};
  float mreg[2] = {-1e30f, -1e30f};
  float lrow[2] = {0.f, 0.f};

  // staging: 1280 16B chunks (640 K + 640 V), 5 per thread
  const u16* gsrc[5];
  u16* ldst[5];
  int step[5];
#pragma unroll
  for (int i = 0; i < 5; ++i) {
    int c = tid + i * 256;
    if (c < 640) {
      int row = c / 10, cc = c - row * 10;
      gsrc[i] = Kp + row * D640 + cc * 8;
      ldst[i] = &Klds[row * 104 + cc * 8];
      step[i] = 64 * D640;
    } else {
      int c2 = c - 640, d = c2 >> 3, cc = c2 & 7;
      gsrc[i] = Vp + d * 1024 + cc * 8;
      ldst[i] = &Vlds[d * 72 + cc * 8];
      step[i] = 64;
    }
  }

  bf16x8 pre[5];
#pragma unroll
  for (int i = 0; i < 5; ++i) pre[i] = *(const bf16x8*)gsrc[i];

  for (int it = 0; it < 16; ++it) {
    __syncthreads();
#pragma unroll
    for (int i = 0; i < 5; ++i) *(bf16x8*)ldst[i] = pre[i];
    __syncthreads();
    if (it < 15) {
#pragma unroll
      for (int i = 0; i < 5; ++i) pre[i] = *(const bf16x8*)(gsrc[i] + (it + 1) * step[i]);
    }

    // QK^T (swapped): st[kb][qb]; lane: q=l15+16qb, keys kb*16+g*4+r
    f32x4 st[4][2];
#pragma unroll
    for (int kb = 0; kb < 4; ++kb)
#pragma unroll
      for (int qb = 0; qb < 2; ++qb) st[kb][qb] = (f32x4){0.f, 0.f, 0.f, 0.f};
    __builtin_amdgcn_s_setprio(1);
#pragma unroll
    for (int dc = 0; dc < 3; ++dc)
#pragma unroll
      for (int kb = 0; kb < 4; ++kb) {
        bf16x8 ka = *(const bf16x8*)&Klds[(kb * 16 + l15) * 104 + dc * 32 + g * 8];
        st[kb][0] = __builtin_amdgcn_mfma_f32_16x16x32_bf16(ka, qreg[0][dc], st[kb][0], 0, 0, 0);
        st[kb][1] = __builtin_amdgcn_mfma_f32_16x16x32_bf16(ka, qreg[1][dc], st[kb][1], 0, 0, 0);
      }
    __builtin_amdgcn_s_setprio(0);

    // tile max per qb
    float mt[2];
#pragma unroll
    for (int qb = 0; qb < 2; ++qb) {
      float m01 = fmaxf(fmaxf(st[0][qb][0], st[0][qb][1]), fmaxf(st[0][qb][2], st[0][qb][3]));
      float m23 = fmaxf(fmaxf(st[1][qb][0], st[1][qb][1]), fmaxf(st[1][qb][2], st[1][qb][3]));
      float m45 = fmaxf(fmaxf(st[2][qb][0], st[2][qb][1]), fmaxf(st[2][qb][2], st[2][qb][3]));
      float m67 = fmaxf(fmaxf(st[3][qb][0], st[3][qb][1]), fmaxf(st[3][qb][2], st[3][qb][3]));
      float m = fmaxf(fmaxf(m01, m23), fmaxf(m45, m67));
      m = fmaxf(m, __shfl_xor(m, 16, 64));
      m = fmaxf(m, __shfl_xor(m, 32, 64));
      mt[qb] = m;
    }

    // defer-max rescale (rare)
    if (__any((mt[0] > mreg[0] + 8.f) || (mt[1] > mreg[1] + 8.f))) {
#pragma unroll
      for (int qb = 0; qb < 2; ++qb) {
        float mn = fmaxf(mreg[qb], mt[qb]);
        float scl = exp2f(mreg[qb] - mn);
        mreg[qb] = mn;
        lrow[qb] *= scl;
        float s_[4];
#pragma unroll
        for (int r = 0; r < 4; ++r)
          s_[r] = __shfl(scl, (lane & 48) | (g * 4 + r), 64);
#pragma unroll
        for (int db = 0; db < 5; ++db)
#pragma unroll
          for (int r = 0; r < 4; ++r) acc[qb][db][r] *= s_[r];
      }
    }

    // P = exp2(S^T - m), accumulate l, pack (cvt_pk), store to per-wave P LDS
#pragma unroll
    for (int qb = 0; qb < 2; ++qb) {
      float sum = 0.f;
#pragma unroll
      for (int kb = 0; kb < 4; ++kb) {
        float p0 = exp2f(st[kb][qb][0] - mreg[qb]);
        float p1 = exp2f(st[kb][qb][1] - mreg[qb]);
        float p2 = exp2f(st[kb][qb][2] - mreg[qb]);
        float p3 = exp2f(st[kb][qb][3] - mreg[qb]);
        sum += (p0 + p1) + (p2 + p3);
        uint2 pk;
        pk.x = pack2(p0, p1);
        pk.y = pack2(p2, p3);
        *(uint2*)&Pw[(l15 + 16 * qb) * 72 + kb * 16 + g * 4] = pk;
      }
      sum += __shfl_xor(sum, 16, 64);
      sum += __shfl_xor(sum, 32, 64);
      lrow[qb] += sum;
    }

    // PV: O[q][d] += P[q][keys] * V^T[d][keys]
    __builtin_amdgcn_s_setprio(1);
#pragma unroll
    for (int kc = 0; kc < 2; ++kc) {
      bf16x8 pa0 = *(const bf16x8*)&Pw[(l15) * 72 + kc * 32 + g * 8];
      bf16x8 pa1 = *(const bf16x8*)&Pw[(l15 + 16) * 72 + kc * 32 + g * 8];
#pragma unroll
      for (int db = 0; db < 5; ++db) {
        bf16x8 bv = *(const bf16x8*)&Vlds[(db * 16 + l15) * 72 + kc * 32 + g * 8];
        acc[0][db] = __builtin_amdgcn_mfma_f32_16x16x32_bf16(pa0, bv, acc[0][db], 0, 0, 0);
        acc[1][db] = __builtin_amdgcn_mfma_f32_16x16x32_bf16(pa1, bv, acc[1][db], 0, 0, 0);
      }
    }
    __builtin_amdgcn_s_setprio(0);
  }

  // epilogue: O rows q = qb*16 + g*4 + r, cols d = db*16 + l15
  u16* Op = AO + (size_t)(f * 1024 + qc * 128 + w * 32) * D640 + h * 80;
#pragma unroll
  for (int qb = 0; qb < 2; ++qb) {
    float i_[4];
#pragma unroll
    for (int r = 0; r < 4; ++r)
      i_[r] = 1.f / __shfl(lrow[qb], (lane & 48) | (g * 4 + r), 64);
#pragma unroll
    for (int db = 0; db < 5; ++db)
#pragma unroll
      for (int r = 0; r < 4; ++r)
        Op[(qb * 16 + g * 4 + r) * D640 + db * 16 + l15] = f2b(acc[qb][db][r] * i_[r]);
  }
}

// ------------------- launcher -------------------
extern "C" void kernel_launch(void* const* d_in, const int* in_sizes, int n_in,
                              void* d_out, int out_size, void* d_ws, size_t ws_size,
                              hipStream_t stream) {
  (void)in_sizes; (void)n_in; (void)out_size; (void)ws_size;
  const void* hs = d_in[0];
  const void* wq = d_in[1];
  const void* wk = d_in[2];
  const void* wv = d_in[3];
  const void* wo = d_in[4];
  const void* bo = d_in[5];
  u16* ws = (u16*)d_ws;

  u16* WT  = ws;                         // 4 * 640*640         bf16
  u16* Qb  = ws + 1638400;               // 16384*640           bf16
  u16* Kb  = Qb + 10485760;              // 2048*640            bf16
  u16* Vb  = Kb + 1310720;               // V^T: 2 grp x [640 col][1024 key]
  u16* AOb = Vb + 1310720;               // 16384*640           bf16
  u32* flag = (u32*)(AOb + 10485760);    // dtype flag

  const float QSCALE = 0.11180339887498949f * 1.44269504088896340f;

  detect_dtype<<<1, 256, 0, stream>>>((const u16*)hs, flag);

  transpose_w<<<dim3(20, 20, 4), dim3(32, 8), 0, stream>>>(wq, wk, wv, wo, WT, flag);

  // Q projection (all 16384 rows), scale folded in
  gemm_bt<<<dim3(128, 5), 256, 0, stream>>>(hs, WT, Qb, QSCALE, nullptr, flag, 0, 1, 0);
  // K and V (V stored transposed) for frames 0 and 8, one dispatch
  gemm_kv<<<dim3(8, 5, 4), 256, 0, stream>>>(hs, WT + 409600, WT + 819200, Kb, Vb, flag);

  attn_kernel<<<dim3(8, 128), 256, 0, stream>>>(Qb, Kb, Vb, AOb);

  // output projection + bias; C dtype follows detected input dtype
  gemm_bt<<<dim3(128, 5), 256, 0, stream>>>(AOb, WT + 1228800, d_out, 1.f, bo, flag, 0, 0, 1);
}